// Round 1
// baseline (4270.966 us; speedup 1.0000x reference)
//
#include <hip/hip_runtime.h>
#include <hip/hip_fp16.h>

#define T_STEPS 512
#define BDIM 512
#define LDIM 512
#define FDIM 128

typedef _Float16 half8 __attribute__((ext_vector_type(8)));
typedef float f4_t __attribute__((ext_vector_type(4)));

// workspace offsets (bytes), all 16B-aligned
#define OFF_WPERM   0u          // 2048*512*2   = 2097152
#define OFF_WDH     2097152u    // 128*512*2    = 131072
#define OFF_BCOMB   2228224u    // 2048*4       = 8192
#define OFF_HBUF0   2236416u    // 512*512*2    = 524288
#define OFF_HBUF1   2760704u    // 512*512*2
#define OFF_CGLOB   3284992u    // 512*512*4    = 1048576
// total ~4.3 MB

__device__ __forceinline__ float sigmoidf_(float x) { return 1.f / (1.f + __expf(-x)); }
__device__ __forceinline__ float tanhf_(float x) { return 1.f - 2.f / (__expf(2.f * x) + 1.f); }

// ---------------- precompute: W_perm = permuted+swizzled fp16 of (W_hh + W_ih@W_dense), b_comb ----------------
// W_perm row pr = sg*4 + gate  (s-major ordering so MFMA C-layout makes i,f,g,o lane-local)
__global__ __launch_bounds__(256) void k_prep_w(
    const float* __restrict__ W_ih, const float* __restrict__ W_hh,
    const float* __restrict__ b_ih, const float* __restrict__ b_hh,
    const float* __restrict__ W_dense, const float* __restrict__ b_dense,
    _Float16* __restrict__ Wperm, float* __restrict__ bcomb)
{
    __shared__ float ih[FDIM];
    const int pr = blockIdx.x;            // 0..2047
    const int gate = pr & 3, sg = pr >> 2;
    const int j = gate * 512 + sg;        // original gate row
    const int tid = threadIdx.x;
    if (tid < FDIM) ih[tid] = W_ih[j * FDIM + tid];
    __syncthreads();
    const int k0 = tid * 2;
    float a0 = W_hh[(size_t)j * LDIM + k0];
    float a1 = W_hh[(size_t)j * LDIM + k0 + 1];
    for (int f = 0; f < FDIM; ++f) {
        const float w = ih[f];
        a0 += w * W_dense[f * LDIM + k0];
        a1 += w * W_dense[f * LDIM + k0 + 1];
    }
    const int s = (pr & 7) << 3;          // element-level XOR swizzle (k0 even, s multiple of 8 -> +1 stays adjacent)
    Wperm[(size_t)pr * LDIM + (k0 ^ s)] = (_Float16)a0;
    Wperm[(size_t)pr * LDIM + (k0 ^ s) + 1] = (_Float16)a1;
    if (tid == 0) {
        float acc = b_ih[j] + b_hh[j];
        for (int f = 0; f < FDIM; ++f) acc += ih[f] * b_dense[f];
        bcomb[j] = acc;
    }
}

// ---------------- precompute: fp16 swizzled W_dense copy + fp16 swizzled h0 ----------------
__global__ __launch_bounds__(256) void k_prep_misc(
    const float* __restrict__ W_dense, const float* __restrict__ h0,
    _Float16* __restrict__ Wdh, _Float16* __restrict__ hbuf0)
{
    const int bid = blockIdx.x, tid = threadIdx.x;
    const int k0 = tid * 2;
    if (bid < FDIM) {
        const int f = bid; const int s = (f & 7) << 3;
        Wdh[f * LDIM + (k0 ^ s)] = (_Float16)W_dense[f * LDIM + k0];
        Wdh[f * LDIM + (k0 ^ s) + 1] = (_Float16)W_dense[f * LDIM + k0 + 1];
    } else {
        const int r = bid - FDIM; const int s = (r & 7) << 3;
        hbuf0[r * LDIM + (k0 ^ s)] = (_Float16)h0[r * LDIM + k0];
        hbuf0[r * LDIM + (k0 ^ s) + 1] = (_Float16)h0[r * LDIM + k0 + 1];
    }
}

// ---------------- one recurrence step ----------------
// grid: (32 col-blocks, 8 row-groups); block: 256 thr = 4 waves in 2x2 (wm, wn)
// block tile: 64 gate-cols (16 L-cols x 4 gates, s-major) x 64 batch rows, K=512
#define LDS_W   0
#define LDS_WD  65536
#define LDS_H   69632
#define LDS_TOT 135168

__global__ __launch_bounds__(256) void k_step(
    const _Float16* __restrict__ Wperm, const _Float16* __restrict__ Wdh,
    const float* __restrict__ bcomb, const float* __restrict__ bdense,
    const _Float16* __restrict__ h_in, _Float16* __restrict__ h_out,
    float* __restrict__ c_glob, float* __restrict__ out, int t)
{
    __shared__ __align__(16) char smem[LDS_TOT];
    const int c = blockIdx.x;       // 0..31
    const int g = blockIdx.y;       // 0..7
    const int tid = threadIdx.x;
    const int w = tid >> 6, lane = tid & 63;
    const int wm = w >> 1, wn = w & 1;
    const int lr = lane & 15, lh = lane >> 4;

    // ---- stage: W slice 64KB, Wd slice 4KB, h slice 64KB (layouts already swizzled in global) ----
    {
        const char* gw = (const char*)Wperm + (size_t)c * 65536;
        #pragma unroll
        for (int i = 0; i < 16; ++i) {
            const int idx = i * 256 + tid;
            *(uint4*)(smem + LDS_W + idx * 16) = *(const uint4*)(gw + idx * 16);
        }
        const char* gd = (const char*)Wdh + (size_t)c * 4096;
        *(uint4*)(smem + LDS_WD + tid * 16) = *(const uint4*)(gd + tid * 16);
        const char* gh = (const char*)h_in + (size_t)g * 65536;
        #pragma unroll
        for (int i = 0; i < 16; ++i) {
            const int idx = i * 256 + tid;
            *(uint4*)(smem + LDS_H + idx * 16) = *(const uint4*)(gh + idx * 16);
        }
    }
    __syncthreads();

    const int ntx = 2 * wn + wm;                 // this wave's x output Ntile (one of its gate Ntiles)
    const int swA = (lr & 7) << 4;               // byte-level swizzle for W/h rows (row&7 == lr&7 here)
    const int swD = ((c * 4 + lr) & 7) << 4;     // Wd uses global row (c*4 not multiple of 8)

    if (t <= T_STEPS) {
        f4_t acc[2][2] = {};                     // [mt2][nt2]
        f4_t accx = {};
        const char* pA0 = smem + LDS_W + ((2 * wm + 0) * 16 + lr) * 1024;
        const char* pA1 = smem + LDS_W + ((2 * wm + 1) * 16 + lr) * 1024;
        const char* pB0 = smem + LDS_H + ((2 * wn + 0) * 16 + lr) * 1024;
        const char* pB1 = smem + LDS_H + ((2 * wn + 1) * 16 + lr) * 1024;
        const char* pD  = smem + LDS_WD + lr * 1024;
        #pragma unroll
        for (int kt = 0; kt < 16; ++kt) {
            const int kb = kt * 64 + lh * 16;
            const half8 a0 = *(const half8*)(pA0 + (kb ^ swA));
            const half8 a1 = *(const half8*)(pA1 + (kb ^ swA));
            const half8 b0 = *(const half8*)(pB0 + (kb ^ swA));
            const half8 b1 = *(const half8*)(pB1 + (kb ^ swA));
            const half8 ad = *(const half8*)(pD + (kb ^ swD));
            acc[0][0] = __builtin_amdgcn_mfma_f32_16x16x32_f16(a0, b0, acc[0][0], 0, 0, 0);
            acc[0][1] = __builtin_amdgcn_mfma_f32_16x16x32_f16(a0, b1, acc[0][1], 0, 0, 0);
            acc[1][0] = __builtin_amdgcn_mfma_f32_16x16x32_f16(a1, b0, acc[1][0], 0, 0, 0);
            acc[1][1] = __builtin_amdgcn_mfma_f32_16x16x32_f16(a1, b1, acc[1][1], 0, 0, 0);
            accx = __builtin_amdgcn_mfma_f32_16x16x32_f16(ad, wm ? b1 : b0, accx, 0, 0, 0);
        }

        // ---- cell update: lane holds i,f,g,o in acc[mt2][nt2][0..3] for (row, L-col) ----
        #pragma unroll
        for (int mt2 = 0; mt2 < 2; ++mt2) {
            const int s_loc = 8 * wm + 4 * mt2 + lh;   // 0..15
            const int sg = c * 16 + s_loc;             // global L-col
            const float bi = bcomb[0 * 512 + sg];
            const float bf = bcomb[1 * 512 + sg];
            const float bg = bcomb[2 * 512 + sg];
            const float bo = bcomb[3 * 512 + sg];
            #pragma unroll
            for (int nt2 = 0; nt2 < 2; ++nt2) {
                const int row = g * 64 + (2 * wn + nt2) * 16 + lr;
                const float iv = sigmoidf_(acc[mt2][nt2][0] + bi);
                const float fv = sigmoidf_(acc[mt2][nt2][1] + bf);
                const float gv = tanhf_(acc[mt2][nt2][2] + bg);
                const float ov = sigmoidf_(acc[mt2][nt2][3] + bo);
                const float cold = c_glob[row * 512 + sg];
                const float cnew = fv * cold + iv * gv;
                const float hnew = ov * tanhf_(cnew);
                c_glob[row * 512 + sg] = cnew;
                h_out[row * 512 + (sg ^ ((row & 7) << 3))] = (_Float16)hnew;  // publish swizzled
            }
        }

        // ---- x_{t-1} = dense(h_{t-1}) -> out[:, t-2, :] (valid rows m<4 live in lanes lh==0) ----
        if (t >= 2 && lh == 0) {
            const int row = g * 64 + ntx * 16 + lr;
            float* o = &out[((size_t)row * T_STEPS + (t - 2)) * FDIM + c * 4];
            o[0] = accx[0] + bdense[c * 4 + 0];
            o[1] = accx[1] + bdense[c * 4 + 1];
            o[2] = accx[2] + bdense[c * 4 + 2];
            o[3] = accx[3] + bdense[c * 4 + 3];
        }
    } else {
        // epilogue: only x_T = dense(h_T) -> out[:, T-1, :]
        f4_t accx = {};
        const char* pD = smem + LDS_WD + lr * 1024;
        const char* pB = smem + LDS_H + (ntx * 16 + lr) * 1024;
        #pragma unroll
        for (int kt = 0; kt < 16; ++kt) {
            const int kb = kt * 64 + lh * 16;
            const half8 ad = *(const half8*)(pD + (kb ^ swD));
            const half8 b = *(const half8*)(pB + (kb ^ swA));
            accx = __builtin_amdgcn_mfma_f32_16x16x32_f16(ad, b, accx, 0, 0, 0);
        }
        if (lh == 0) {
            const int row = g * 64 + ntx * 16 + lr;
            float* o = &out[((size_t)row * T_STEPS + (T_STEPS - 1)) * FDIM + c * 4];
            o[0] = accx[0] + bdense[c * 4 + 0];
            o[1] = accx[1] + bdense[c * 4 + 1];
            o[2] = accx[2] + bdense[c * 4 + 2];
            o[3] = accx[3] + bdense[c * 4 + 3];
        }
    }
}

extern "C" void kernel_launch(void* const* d_in, const int* in_sizes, int n_in,
                              void* d_out, int out_size, void* d_ws, size_t ws_size,
                              hipStream_t stream)
{
    const float* h0      = (const float*)d_in[0];
    const float* c0      = (const float*)d_in[1];
    const float* W_ih    = (const float*)d_in[2];
    const float* W_hh    = (const float*)d_in[3];
    const float* b_ih    = (const float*)d_in[4];
    const float* b_hh    = (const float*)d_in[5];
    const float* W_dense = (const float*)d_in[6];
    const float* b_dense = (const float*)d_in[7];
    float* out = (float*)d_out;
    char* ws = (char*)d_ws;

    _Float16* Wperm = (_Float16*)(ws + OFF_WPERM);
    _Float16* Wdh   = (_Float16*)(ws + OFF_WDH);
    float*    bcomb = (float*)(ws + OFF_BCOMB);
    _Float16* hb0   = (_Float16*)(ws + OFF_HBUF0);
    _Float16* hb1   = (_Float16*)(ws + OFF_HBUF1);
    float*    cg    = (float*)(ws + OFF_CGLOB);

    // c state init (re-poisoned every launch, so recompute everything)
    hipMemcpyAsync(cg, c0, (size_t)BDIM * LDIM * sizeof(float), hipMemcpyDeviceToDevice, stream);
    k_prep_w<<<2048, 256, 0, stream>>>(W_ih, W_hh, b_ih, b_hh, W_dense, b_dense, Wperm, bcomb);
    k_prep_misc<<<FDIM + BDIM, 256, 0, stream>>>(W_dense, h0, Wdh, hb0);

    for (int t = 1; t <= T_STEPS + 1; ++t) {
        const _Float16* hin = ((t - 1) & 1) ? hb1 : hb0;
        _Float16* hout = (t & 1) ? hb1 : hb0;
        k_step<<<dim3(32, 8), 256, 0, stream>>>(Wperm, Wdh, bcomb, b_dense, hin, hout, cg, out, t);
    }
}